// Round 6
// baseline (310.595 us; speedup 1.0000x reference)
//
#include <hip/hip_runtime.h>

#define NN 30000
#define NE 120000
#define NG 256
#define FIN 16
#define HD 32
#define TOUT 10
#define EPSV 1e-5f
#define CAP 32        // bucket capacity per node (deg ~ Poisson(4); P(>=32) ~ 1e-16)

__device__ __forceinline__ void atomAddF(float* p, float v) {
    unsafeAtomicAdd(p, v);  // global_atomic_add_f32
}

// ===========================================================================
// Init: all DIRECT stores. cursor[d] = d*CAP; pooled = 0; deg_g[g] via binary
// search on the sorted batch array.
// ===========================================================================
__global__ __launch_bounds__(256) void init_kernel(
    const int* __restrict__ batch,     // [NN] sorted
    int*   __restrict__ cursor,        // [NN]
    float* __restrict__ deg_g,         // [NG]
    float* __restrict__ pooled)        // [NG*HD]
{
    const int t = blockIdx.x * 256 + threadIdx.x;

    if (t < NN) cursor[t] = t * CAP;
    if (t < NG * HD) pooled[t] = 0.0f;

    if (t < NG) {
        int lo = 0, hi = NN;
        while (lo < hi) { const int m = (lo + hi) >> 1;
                          if (batch[m] < t) lo = m + 1; else hi = m; }
        const int b0 = lo;
        lo = 0; hi = NN;
        while (lo < hi) { const int m = (lo + hi) >> 1;
                          if (batch[m] < t + 1) lo = m + 1; else hi = m; }
        deg_g[t] = (float)(lo - b0);
    }
}

// ---------------------------------------------------------------------------
// Scatter edges + edge attrs into per-node buckets (src_b / ea_b).
// ---------------------------------------------------------------------------
__global__ __launch_bounds__(256) void bucket_scatter(
    const int* __restrict__ eidx, const float* __restrict__ ea,
    int* __restrict__ cursor,
    int* __restrict__ src_b,      // [NN*CAP]
    float4* __restrict__ ea_b)    // [NN*CAP*2]
{
    const int e = blockIdx.x * 256 + threadIdx.x;
    if (e >= NE) return;
    const int d = eidx[NE + e];
    const int slot = atomicAdd(&cursor[d], 1);
    if (slot < d * CAP + CAP) {
        src_b[slot] = eidx[e];
        const float4* s4 = (const float4*)(ea + (size_t)e * 8);
        ea_b[2 * slot]     = s4[0];
        ea_b[2 * slot + 1] = s4[1];
    }
}

// ===========================================================================
// Phase A as standalone kernel: half-wave (32 lanes) per node, depth-2
// pipelined edge walk (round-0 proven inner loop).  NO LDS, NO barrier ->
// ~8 waves/SIMD; gather latency hidden by wave parallelism.
// Output: T[d][k], k = f*IN+i (f<9: edge sums; f=9: own row for root term).
// ===========================================================================
template<int IN>
__global__ __launch_bounds__(256) void gather_T(
    const float* __restrict__ hin,       // [NN, IN]
    const int*   __restrict__ src_b,     // [NN*CAP]
    const float4* __restrict__ ea_b,     // [NN*CAP*2]
    const int*   __restrict__ cursor,    // [NN] bucket end pointers
    float*       __restrict__ T)         // [NN, 10*IN]
{
    constexpr int K  = 10 * IN;
    constexpr int NQ = 32 / IN;   // edge subgroups per half-wave (2 or 1)

    const int tid = threadIdx.x;
    const int hw  = tid >> 5;          // half-wave 0..7
    const int l5  = tid & 31;
    const int d   = blockIdx.x * 8 + hw;   // NN % 8 == 0

    const int i = l5 & (IN - 1);
    const int q = l5 / IN;

    float t[9];
    #pragma unroll
    for (int f = 0; f < 9; ++f) t[f] = 0.0f;

    const int p0 = d * CAP;
    int p1 = cursor[d];
    p1 = (p1 < p0 + CAP) ? p1 : (p0 + CAP);

    int p = p0 + q;
    if (p < p1) {
        const int pe = p1 - 1;
        int pn     = p + NQ;
        int pnc    = (pn < pe) ? pn : pe;
        int s_cur  = src_b[p];
        int s_nxt  = src_b[pnc];
        float4 a_c = ea_b[2 * p];
        float4 b_c = ea_b[2 * p + 1];
        float  xv  = hin[(long)s_cur * IN + i];

        while (true) {
            const float4 a_n = ea_b[2 * pnc];
            const float4 b_n = ea_b[2 * pnc + 1];
            const float  xvn = hin[(long)s_nxt * IN + i];
            const int pn2    = pn + NQ;
            const int pn2c   = (pn2 < pe) ? pn2 : pe;
            const int s_n2   = src_b[pn2c];

            t[0] = fmaf(a_c.x, xv, t[0]);
            t[1] = fmaf(a_c.y, xv, t[1]);
            t[2] = fmaf(a_c.z, xv, t[2]);
            t[3] = fmaf(a_c.w, xv, t[3]);
            t[4] = fmaf(b_c.x, xv, t[4]);
            t[5] = fmaf(b_c.y, xv, t[5]);
            t[6] = fmaf(b_c.z, xv, t[6]);
            t[7] = fmaf(b_c.w, xv, t[7]);
            t[8] += xv;

            p = pn;
            if (p >= p1) break;
            pn = pn2; pnc = pn2c; s_nxt = s_n2;
            a_c = a_n; b_c = b_n; xv = xvn;
        }
    }

    if (IN == 16) {   // combine the 2 edge subgroups (same i)
        #pragma unroll
        for (int f = 0; f < 9; ++f) t[f] += __shfl_xor(t[f], 16, 64);
    }

    if (l5 < IN) {
        float* tb = T + (long)d * K;
        #pragma unroll
        for (int f = 0; f < 9; ++f) tb[f * IN + i] = t[f];
        tb[9 * IN + i] = hin[(long)d * IN + i];   // own row (root term)
    }
}

// ===========================================================================
// Phase B as standalone kernel: round-0 proven k-sliced GEMM, but T rows read
// from GLOBAL via broadcast loads (64B fetch shared by 32 lanes, L2-streamed).
// LDS = only P (16 KB) -> 8 blocks/CU.  Epilogue: gsn+BN+ReLU or pool atomics.
// ===========================================================================
template<int IN, bool FINAL>
__global__ __launch_bounds__(256) void gemm_out(
    const float* __restrict__ T,         // [NN, 10*IN]
    const float* __restrict__ nn_w,      // [8*IN*32] flat k*32+o
    const float* __restrict__ nn_b,      // [IN*32]
    const float* __restrict__ root,      // [IN*32]
    const float* __restrict__ bias,      // [32]
    const int*   __restrict__ batch,
    const float* __restrict__ deg_g,     // [NG]
    const float* __restrict__ bn_g,
    const float* __restrict__ bn_b,
    const float* __restrict__ bn_m,
    const float* __restrict__ bn_v,
    float*       __restrict__ out)       // [NN,32] or pooled [NG,32]
{
    constexpr int K  = 10 * IN;
    constexpr int KQ = K / 4;
    constexpr int KL = KQ / 2;

    __shared__ float P[4 * 16 * 64];

    const int tid = threadIdx.x;
    const int wv  = tid >> 6;
    const int l   = tid & 63;
    const int h   = l >> 5;
    const int o   = l & 31;

    // ---- W slice into registers (L2-hot global loads, once per block) ----
    float Wreg[KL];
    const int kbase = wv * KQ + h * KL;
    #pragma unroll
    for (int kk = 0; kk < KL; ++kk) {
        const int k = kbase + kk;
        const float* src = (k < 8 * IN) ? (nn_w + k * 32)
                         : (k < 9 * IN) ? (nn_b + (k - 8 * IN) * 32)
                                        : (root + (k - 9 * IN) * 32);
        Wreg[kk] = src[o];
    }

    // ---- partial GEMM over this wave's k-slice (T from global) ----------
    for (int n = 0; n < 16; ++n) {
        const float* tb = T + (long)(blockIdx.x * 16 + n) * K + kbase;
        float acc = 0.0f;
        #pragma unroll
        for (int kq = 0; kq < KL / 4; ++kq) {
            const float4 tv = *(const float4*)(tb + kq * 4);
            acc = fmaf(Wreg[4 * kq + 0], tv.x, acc);
            acc = fmaf(Wreg[4 * kq + 1], tv.y, acc);
            acc = fmaf(Wreg[4 * kq + 2], tv.z, acc);
            acc = fmaf(Wreg[4 * kq + 3], tv.w, acc);
        }
        P[(wv * 16 + n) * 64 + l] = acc;
    }
    __syncthreads();

    // ---- reduce partials + epilogue -------------------------------------
    #pragma unroll
    for (int r = 0; r < 2; ++r) {
        const int idx = r * 256 + tid;          // 512 (n,o) pairs
        const int n   = idx >> 5;
        const int oo  = idx & 31;
        float sum = bias[oo];
        #pragma unroll
        for (int ww = 0; ww < 4; ++ww) {
            const float* pb = P + (ww * 16 + n) * 64;
            sum += pb[oo] + pb[32 + oo];
        }
        const int d = blockIdx.x * 16 + n;
        const int g = batch[d];
        if (!FINAL) {
            float dg = deg_g[g];
            dg = dg > 0.0f ? dg : 1.0f;
            float v = sum * (1.0f / sqrtf(dg));
            const float s = bn_g[oo] / sqrtf(bn_v[oo] + EPSV);
            v = (v - bn_m[oo]) * s + bn_b[oo];
            out[(long)d * 32 + oo] = v > 0.0f ? v : 0.0f;
        } else {
            float v = sum;
            const int   g2 = __shfl(g, (tid & 63) ^ 32, 64);
            const float v2 = __shfl(v, (tid & 63) ^ 32, 64);
            bool do_store = true;
            if (g2 == g) {                  // merge adjacent-node pair
                if (tid & 32) do_store = false;
                else          v += v2;
            }
            if (do_store) atomAddF(&out[g * 32 + oo], v);
        }
    }
}

// ---------------------------------------------------------------------------
// Head: pooled/cnt -> relu(@w1+b1) @ w2 + b2. One thread per graph.
// ---------------------------------------------------------------------------
__global__ __launch_bounds__(64) void head_kernel(
    const float* __restrict__ pooled,
    const float* __restrict__ deg,
    const float* __restrict__ w1,
    const float* __restrict__ b1,
    const float* __restrict__ w2,
    const float* __restrict__ b2,
    float*       __restrict__ out)
{
    const int g = blockIdx.x * 64 + threadIdx.x;
    if (g >= NG) return;
    float cnt = deg[g];
    cnt = cnt > 1.0f ? cnt : 1.0f;

    float p[HD];
    #pragma unroll
    for (int i = 0; i < HD; ++i) p[i] = pooled[g * HD + i] / cnt;

    float hid[HD];
    #pragma unroll
    for (int j = 0; j < HD; ++j) {
        float a = b1[j];
        #pragma unroll
        for (int i = 0; i < HD; ++i)
            a = fmaf(p[i], w1[i * HD + j], a);
        hid[j] = a > 0.0f ? a : 0.0f;
    }
    #pragma unroll
    for (int t = 0; t < TOUT; ++t) {
        float a = b2[t];
        #pragma unroll
        for (int j = 0; j < HD; ++j)
            a = fmaf(hid[j], w2[j * TOUT + t], a);
        out[g * TOUT + t] = a;
    }
}

// ---------------------------------------------------------------------------
extern "C" void kernel_launch(void* const* d_in, const int* in_sizes, int n_in,
                              void* d_out, int out_size, void* d_ws, size_t ws_size,
                              hipStream_t stream)
{
    const float* x        = (const float*)d_in[0];
    const float* ea       = (const float*)d_in[1];
    const int*   eidx     = (const int*)  d_in[2];
    const int*   batch    = (const int*)  d_in[3];
    const float* c1_nn_w  = (const float*)d_in[4];
    const float* c1_nn_b  = (const float*)d_in[5];
    const float* c1_root  = (const float*)d_in[6];
    const float* c1_bias  = (const float*)d_in[7];
    const float* c2_nn_w  = (const float*)d_in[8];
    const float* c2_nn_b  = (const float*)d_in[9];
    const float* c2_root  = (const float*)d_in[10];
    const float* c2_bias  = (const float*)d_in[11];
    const float* c3_nn_w  = (const float*)d_in[12];
    const float* c3_nn_b  = (const float*)d_in[13];
    const float* c3_root  = (const float*)d_in[14];
    const float* c3_bias  = (const float*)d_in[15];
    const float* bn1_g    = (const float*)d_in[16];
    const float* bn1_b    = (const float*)d_in[17];
    const float* bn1_m    = (const float*)d_in[18];
    const float* bn1_v    = (const float*)d_in[19];
    const float* bn2_g    = (const float*)d_in[20];
    const float* bn2_b    = (const float*)d_in[21];
    const float* bn2_m    = (const float*)d_in[22];
    const float* bn2_v    = (const float*)d_in[23];
    const float* mlp_w1   = (const float*)d_in[24];
    const float* mlp_b1   = (const float*)d_in[25];
    const float* mlp_w2   = (const float*)d_in[26];
    const float* mlp_b2   = (const float*)d_in[27];
    float* out = (float*)d_out;

    // workspace layout (16B alignment preserved)
    float*  h1     = (float*)d_ws;                   // NN*32
    float*  h2     = h1 + NN * HD;                   // NN*32
    float4* ea_b   = (float4*)(h2 + NN * HD);        // NN*CAP*2 float4 (30.7MB)
    int*    src_b  = (int*)(ea_b + 2 * NN * CAP);    // NN*CAP
    int*    cursor = src_b + NN * CAP;               // NN
    float*  deg_g  = (float*)(cursor + NN);          // NG
    float*  pooled = deg_g + NG;                     // NG*32
    float*  T      = pooled + NG * HD;               // NN*320 (38.4 MB), reused

    const int egrid = (NE + 255) / 256;

    init_kernel<<<(NN + 255) / 256, 256, 0, stream>>>(batch, cursor, deg_g, pooled);

    bucket_scatter<<<egrid, 256, 0, stream>>>(eidx, ea, cursor, src_b, ea_b);

    const int agrid = NN / 8;   // 3750 blocks, 8 nodes (half-waves) each
    const int bgrid = NN / 16;  // 1875 blocks, 16 nodes each

    // ---- layer 1 (IN=16) ----
    gather_T<FIN><<<agrid, 256, 0, stream>>>(x, src_b, ea_b, cursor, T);
    gemm_out<FIN, false><<<bgrid, 256, 0, stream>>>(
        T, c1_nn_w, c1_nn_b, c1_root, c1_bias,
        batch, deg_g, bn1_g, bn1_b, bn1_m, bn1_v, h1);

    // ---- layer 2 (IN=32) ----
    gather_T<HD><<<agrid, 256, 0, stream>>>(h1, src_b, ea_b, cursor, T);
    gemm_out<HD, false><<<bgrid, 256, 0, stream>>>(
        T, c2_nn_w, c2_nn_b, c2_root, c2_bias,
        batch, deg_g, bn2_g, bn2_b, bn2_m, bn2_v, h2);

    // ---- layer 3 (IN=32, pooled output) ----
    gather_T<HD><<<agrid, 256, 0, stream>>>(h2, src_b, ea_b, cursor, T);
    gemm_out<HD, true><<<bgrid, 256, 0, stream>>>(
        T, c3_nn_w, c3_nn_b, c3_root, c3_bias,
        batch, deg_g, nullptr, nullptr, nullptr, nullptr, pooled);

    head_kernel<<<(NG + 63) / 64, 64, 0, stream>>>(pooled, deg_g, mlp_w1, mlp_b1,
                                                   mlp_w2, mlp_b2, out);
}

// Round 7
// 238.293 us; speedup vs baseline: 1.3034x; 1.3034x over previous
//
#include <hip/hip_runtime.h>

#define NN 30000
#define NE 120000
#define NG 256
#define FIN 16
#define HD 32
#define TOUT 10
#define EPSV 1e-5f
#define CAP 32        // bucket capacity per node (deg ~ Poisson(4); P(>=32) ~ 1e-16)

__device__ __forceinline__ void atomAddF(float* p, float v) {
    unsafeAtomicAdd(p, v);  // global_atomic_add_f32
}

// ===========================================================================
// Init: all DIRECT stores. cursor[d] = d*CAP; pooled = 0; deg_g[g] via binary
// search on the sorted batch array.
// ===========================================================================
__global__ __launch_bounds__(256) void init_kernel(
    const int* __restrict__ batch,     // [NN] sorted
    int*   __restrict__ cursor,        // [NN]
    float* __restrict__ deg_g,         // [NG]
    float* __restrict__ pooled)        // [NG*HD]
{
    const int t = blockIdx.x * 256 + threadIdx.x;

    if (t < NN) cursor[t] = t * CAP;
    if (t < NG * HD) pooled[t] = 0.0f;

    if (t < NG) {
        int lo = 0, hi = NN;
        while (lo < hi) { const int m = (lo + hi) >> 1;
                          if (batch[m] < t) lo = m + 1; else hi = m; }
        const int b0 = lo;
        lo = 0; hi = NN;
        while (lo < hi) { const int m = (lo + hi) >> 1;
                          if (batch[m] < t + 1) lo = m + 1; else hi = m; }
        deg_g[t] = (float)(lo - b0);
    }
}

// ---------------------------------------------------------------------------
// Scatter edges + edge attrs into per-node buckets (src_b / ea_b).
// ---------------------------------------------------------------------------
__global__ __launch_bounds__(256) void bucket_scatter(
    const int* __restrict__ eidx, const float* __restrict__ ea,
    int* __restrict__ cursor,
    int* __restrict__ src_b,      // [NN*CAP]
    float4* __restrict__ ea_b)    // [NN*CAP*2]
{
    const int e = blockIdx.x * 256 + threadIdx.x;
    if (e >= NE) return;
    const int d = eidx[NE + e];
    const int slot = atomicAdd(&cursor[d], 1);
    if (slot < d * CAP + CAP) {
        src_b[slot] = eidx[e];
        const float4* s4 = (const float4*)(ea + (size_t)e * 8);
        ea_b[2 * slot]     = s4[0];
        ea_b[2 * slot + 1] = s4[1];
    }
}

// ===========================================================================
// Fused layer (round-5 proven structure + ADDRESS-FIRST PREFETCH).
// Block = 16 nodes, 4 waves.
// Prefetch: per half-wave node, ONE coalesced load of the whole src-id list
//           (bucket slots are contiguous), then one touch per ea slot and one
//           per gathered x row -> all of the node's far-memory lines in
//           flight IN PARALLEL while the W-register load executes. The walk
//           then runs L2-hot. Touch values kept alive via asm sink at
//           phase-A end (no wait until then).
// Phase A:  wave handles 4 nodes (2 halves x 2 j); depth-2 pipelined edge
//           walk (proven round-0 loop).
// Phase B:  k = f*IN+i flattened; k split 4 ways across waves; W slice in
//           registers; T broadcast ds_read_b128 -> P -> block reduce +
//           epilogue (gsn+BN+ReLU, or pool atomics).
// ===========================================================================
template<int IN, bool FINAL>
__global__ __launch_bounds__(256) void fused_layer(
    const float* __restrict__ hin,       // [NN, IN]
    const int*   __restrict__ src_b,     // [NN*CAP] bucketed src ids
    const float4* __restrict__ ea_b,     // [NN*CAP*2] bucketed edge attrs
    const int*   __restrict__ cursor,    // [NN] bucket end pointers
    const float* __restrict__ nn_w,      // [8*IN*32] flat k*32+o
    const float* __restrict__ nn_b,      // [IN*32]
    const float* __restrict__ root,      // [IN*32]
    const float* __restrict__ bias,      // [32]
    const int*   __restrict__ batch,
    const float* __restrict__ deg_g,     // [NG]
    const float* __restrict__ bn_g,
    const float* __restrict__ bn_b,
    const float* __restrict__ bn_m,
    const float* __restrict__ bn_v,
    float*       __restrict__ out)       // [NN,32] or pooled [NG,32]
{
    constexpr int K  = 10 * IN;
    constexpr int KQ = K / 4;
    constexpr int KL = KQ / 2;
    constexpr int NQ = 32 / IN;   // edge subgroups per node (2 or 1)

    __shared__ float Tlds[16 * K];
    __shared__ float P[4 * 16 * 64];

    const int tid = threadIdx.x;
    const int wv  = tid >> 6;
    const int l   = tid & 63;
    const int h   = l >> 5;
    const int o   = l & 31;
    const int l5  = l & 31;
    const int pr  = l >> 5;
    const int b16 = blockIdx.x * 16;

    // ---- prefetch preamble: issue all far-memory touches for this thread's
    //      2 nodes before anything else ---------------------------------
    int   p0c[2], p1c[2];
    float tea_pf[2], tx_pf[2];
    #pragma unroll
    for (int j = 0; j < 2; ++j) {
        const int nloc = wv * 4 + j * 2 + pr;
        const int d    = b16 + nloc;
        const int p0   = d * CAP;
        int p1 = cursor[d];
        p1 = (p1 < p0 + CAP) ? p1 : (p0 + CAP);
        p0c[j] = p0; p1c[j] = p1;
        const int deg = p1 - p0;
        float tea = 0.0f, tx = 0.0f;
        if (l5 < deg) {
            const int sl = p0 + l5;                       // coalesced
            const int sid = src_b[sl];                    // whole id list, 1 load
            tea = ((const float*)(ea_b + 2 * sl))[0];     // touch ea line
            tx  = hin[(long)sid * IN];                    // touch x row line
        }
        tea_pf[j] = tea; tx_pf[j] = tx;
    }

    // ---- W slice into registers (independent work under the prefetch) ----
    float Wreg[KL];
    const int kbase = wv * KQ + h * KL;
    #pragma unroll
    for (int kk = 0; kk < KL; ++kk) {
        const int k = kbase + kk;
        const float* src = (k < 8 * IN) ? (nn_w + k * 32)
                         : (k < 9 * IN) ? (nn_b + (k - 8 * IN) * 32)
                                        : (root + (k - 9 * IN) * 32);
        Wreg[kk] = src[o];
    }

    // ---------------- phase A ------------------------------------------
    const int i = l5 & (IN - 1);
    const int q = l5 / IN;

    #pragma unroll
    for (int j = 0; j < 2; ++j) {
        const int nloc = wv * 4 + j * 2 + pr;
        const int d    = b16 + nloc;

        float t[9];
        #pragma unroll
        for (int f = 0; f < 9; ++f) t[f] = 0.0f;

        const int p0 = p0c[j];
        const int p1 = p1c[j];

        int p = p0 + q;
        if (p < p1) {
            const int pe = p1 - 1;
            int pn     = p + NQ;
            int pnc    = (pn < pe) ? pn : pe;
            int s_cur  = src_b[p];
            int s_nxt  = src_b[pnc];
            float4 a_c = ea_b[2 * p];
            float4 b_c = ea_b[2 * p + 1];
            float  xv  = hin[(long)s_cur * IN + i];

            while (true) {
                const float4 a_n = ea_b[2 * pnc];
                const float4 b_n = ea_b[2 * pnc + 1];
                const float  xvn = hin[(long)s_nxt * IN + i];
                const int pn2    = pn + NQ;
                const int pn2c   = (pn2 < pe) ? pn2 : pe;
                const int s_n2   = src_b[pn2c];

                t[0] = fmaf(a_c.x, xv, t[0]);
                t[1] = fmaf(a_c.y, xv, t[1]);
                t[2] = fmaf(a_c.z, xv, t[2]);
                t[3] = fmaf(a_c.w, xv, t[3]);
                t[4] = fmaf(b_c.x, xv, t[4]);
                t[5] = fmaf(b_c.y, xv, t[5]);
                t[6] = fmaf(b_c.z, xv, t[6]);
                t[7] = fmaf(b_c.w, xv, t[7]);
                t[8] += xv;

                p = pn;
                if (p >= p1) break;
                pn = pn2; pnc = pn2c; s_nxt = s_n2;
                a_c = a_n; b_c = b_n; xv = xvn;
            }
        }

        if (IN == 16) {   // combine the 2 edge subgroups (same i)
            #pragma unroll
            for (int f = 0; f < 9; ++f) t[f] += __shfl_xor(t[f], 16, 64);
        }

        if (l5 < IN) {
            float* tb = Tlds + nloc * K;
            #pragma unroll
            for (int f = 0; f < 9; ++f) tb[f * IN + i] = t[f];
            tb[9 * IN + i] = hin[(long)d * IN + i];   // own row (root term)
        }
    }
    // keep prefetch touches alive without earlier waits (rule #17)
    asm volatile("" :: "v"(tea_pf[0]), "v"(tea_pf[1]),
                       "v"(tx_pf[0]),  "v"(tx_pf[1]));
    __syncthreads();

    // ---------------- phase B: partial GEMM over this wave's k-slice ------
    for (int n = 0; n < 16; ++n) {
        const float* tb = Tlds + n * K + kbase;
        float acc = 0.0f;
        #pragma unroll
        for (int kq = 0; kq < KL / 4; ++kq) {
            const float4 tv = *(const float4*)(tb + kq * 4);
            acc = fmaf(Wreg[4 * kq + 0], tv.x, acc);
            acc = fmaf(Wreg[4 * kq + 1], tv.y, acc);
            acc = fmaf(Wreg[4 * kq + 2], tv.z, acc);
            acc = fmaf(Wreg[4 * kq + 3], tv.w, acc);
        }
        P[(wv * 16 + n) * 64 + l] = acc;
    }
    __syncthreads();

    // ---------------- reduce partials + epilogue ---------------------------
    #pragma unroll
    for (int r = 0; r < 2; ++r) {
        const int idx = r * 256 + tid;          // 512 (n,o) pairs
        const int n   = idx >> 5;
        const int oo  = idx & 31;
        float sum = bias[oo];
        #pragma unroll
        for (int ww = 0; ww < 4; ++ww) {
            const float* pb = P + (ww * 16 + n) * 64;
            sum += pb[oo] + pb[32 + oo];
        }
        const int d = b16 + n;
        const int g = batch[d];
        if (!FINAL) {
            float dg = deg_g[g];
            dg = dg > 0.0f ? dg : 1.0f;
            float v = sum * (1.0f / sqrtf(dg));
            const float s = bn_g[oo] / sqrtf(bn_v[oo] + EPSV);
            v = (v - bn_m[oo]) * s + bn_b[oo];
            out[(long)d * 32 + oo] = v > 0.0f ? v : 0.0f;
        } else {
            float v = sum;
            const int   g2 = __shfl(g, (tid & 63) ^ 32, 64);
            const float v2 = __shfl(v, (tid & 63) ^ 32, 64);
            bool do_store = true;
            if (g2 == g) {                  // merge adjacent-node pair
                if (tid & 32) do_store = false;
                else          v += v2;
            }
            if (do_store) atomAddF(&out[g * 32 + oo], v);
        }
    }
}

// ---------------------------------------------------------------------------
// Head: pooled/cnt -> relu(@w1+b1) @ w2 + b2. One thread per graph.
// ---------------------------------------------------------------------------
__global__ __launch_bounds__(64) void head_kernel(
    const float* __restrict__ pooled,
    const float* __restrict__ deg,
    const float* __restrict__ w1,
    const float* __restrict__ b1,
    const float* __restrict__ w2,
    const float* __restrict__ b2,
    float*       __restrict__ out)
{
    const int g = blockIdx.x * 64 + threadIdx.x;
    if (g >= NG) return;
    float cnt = deg[g];
    cnt = cnt > 1.0f ? cnt : 1.0f;

    float p[HD];
    #pragma unroll
    for (int i = 0; i < HD; ++i) p[i] = pooled[g * HD + i] / cnt;

    float hid[HD];
    #pragma unroll
    for (int j = 0; j < HD; ++j) {
        float a = b1[j];
        #pragma unroll
        for (int i = 0; i < HD; ++i)
            a = fmaf(p[i], w1[i * HD + j], a);
        hid[j] = a > 0.0f ? a : 0.0f;
    }
    #pragma unroll
    for (int t = 0; t < TOUT; ++t) {
        float a = b2[t];
        #pragma unroll
        for (int j = 0; j < HD; ++j)
            a = fmaf(hid[j], w2[j * TOUT + t], a);
        out[g * TOUT + t] = a;
    }
}

// ---------------------------------------------------------------------------
extern "C" void kernel_launch(void* const* d_in, const int* in_sizes, int n_in,
                              void* d_out, int out_size, void* d_ws, size_t ws_size,
                              hipStream_t stream)
{
    const float* x        = (const float*)d_in[0];
    const float* ea       = (const float*)d_in[1];
    const int*   eidx     = (const int*)  d_in[2];
    const int*   batch    = (const int*)  d_in[3];
    const float* c1_nn_w  = (const float*)d_in[4];
    const float* c1_nn_b  = (const float*)d_in[5];
    const float* c1_root  = (const float*)d_in[6];
    const float* c1_bias  = (const float*)d_in[7];
    const float* c2_nn_w  = (const float*)d_in[8];
    const float* c2_nn_b  = (const float*)d_in[9];
    const float* c2_root  = (const float*)d_in[10];
    const float* c2_bias  = (const float*)d_in[11];
    const float* c3_nn_w  = (const float*)d_in[12];
    const float* c3_nn_b  = (const float*)d_in[13];
    const float* c3_root  = (const float*)d_in[14];
    const float* c3_bias  = (const float*)d_in[15];
    const float* bn1_g    = (const float*)d_in[16];
    const float* bn1_b    = (const float*)d_in[17];
    const float* bn1_m    = (const float*)d_in[18];
    const float* bn1_v    = (const float*)d_in[19];
    const float* bn2_g    = (const float*)d_in[20];
    const float* bn2_b    = (const float*)d_in[21];
    const float* bn2_m    = (const float*)d_in[22];
    const float* bn2_v    = (const float*)d_in[23];
    const float* mlp_w1   = (const float*)d_in[24];
    const float* mlp_b1   = (const float*)d_in[25];
    const float* mlp_w2   = (const float*)d_in[26];
    const float* mlp_b2   = (const float*)d_in[27];
    float* out = (float*)d_out;

    // workspace layout (16B alignment preserved)
    float*  h1     = (float*)d_ws;                   // NN*32
    float*  h2     = h1 + NN * HD;                   // NN*32
    float4* ea_b   = (float4*)(h2 + NN * HD);        // NN*CAP*2 float4 (30.7MB)
    int*    src_b  = (int*)(ea_b + 2 * NN * CAP);    // NN*CAP
    int*    cursor = src_b + NN * CAP;               // NN
    float*  deg_g  = (float*)(cursor + NN);          // NG
    float*  pooled = deg_g + NG;                     // NG*32

    const int egrid = (NE + 255) / 256;

    init_kernel<<<(NN + 255) / 256, 256, 0, stream>>>(batch, cursor, deg_g, pooled);

    bucket_scatter<<<egrid, 256, 0, stream>>>(eidx, ea, cursor, src_b, ea_b);

    const int lgrid = NN / 16;  // 1875 blocks, 16 nodes each

    fused_layer<FIN, false><<<lgrid, 256, 0, stream>>>(
        x, src_b, ea_b, cursor, c1_nn_w, c1_nn_b, c1_root, c1_bias,
        batch, deg_g, bn1_g, bn1_b, bn1_m, bn1_v, h1);

    fused_layer<HD, false><<<lgrid, 256, 0, stream>>>(
        h1, src_b, ea_b, cursor, c2_nn_w, c2_nn_b, c2_root, c2_bias,
        batch, deg_g, bn2_g, bn2_b, bn2_m, bn2_v, h2);

    fused_layer<HD, true><<<lgrid, 256, 0, stream>>>(
        h2, src_b, ea_b, cursor, c3_nn_w, c3_nn_b, c3_root, c3_bias,
        batch, deg_g, nullptr, nullptr, nullptr, nullptr, pooled);

    head_kernel<<<(NG + 63) / 64, 64, 0, stream>>>(pooled, deg_g, mlp_w1, mlp_b1,
                                                   mlp_w2, mlp_b2, out);
}